// Round 1
// baseline (768.172 us; speedup 1.0000x reference)
//
#include <hip/hip_runtime.h>
#include <hip/hip_bf16.h>
#include <math.h>

// GLA cross-attention — round 8:
//  attn_mfma_split rework (everything else byte-identical to PASSING r7):
//   (a) unpadded XOR-swizzled LDS tiles (col ^= (row&7)<<3 in shorts):
//       Ks 64x128 + VsT 128x64 + Ps 4x16x64 = 40960 B -> 4 blocks/CU (was 3),
//       and conflict-free b128 reads/writes (bank-verified for all patterns).
//   (b) reg-prefetch of next K/V tile issued right after the stage barrier;
//       HBM latency hides under QK^T+softmax+PV (T14 async-stage split).
//   (c) dropped the softmax->PV barrier: Ps is wave-private (indexed by w),
//       intra-wave lgkmcnt ordering suffices.
//   (d) defer-max rescale (T13, THR=8): skip alpha-rescale of accO unless the
//       tile max really grows; merge stays exact (m,l pairs self-consistent).
//   (e) __launch_bounds__(256,4) so VGPR<=128 and the 4-block LDS occupancy
//       is actually reachable.
//
// ws float-offset map (alias notes; top = 49,807,360 f = 199.2 MB):
//   attn_out_b u16 @ 0          (4,194,304 u -> 2,097,152 f)
//   ml        f32 @ 2,097,152   (131,072 f)   [attn stage only; gap before Wot]
//   Wot       u16 @ f4,194,304  (4,194,304 u) [stage 15+]
//   xkvb      u16 @ 0           dead after stage 9 (aliases the above, disjoint in time)
//   ckv       f32 @ 8,388,608   (8,388,608 f) dead after stage 10
//   Opart     f32 @ 8,388,608   (8,388,608 f) [attn stage; aliases dead ckv]
//   xqb/WdQt/q_lat/q_lat_b/WuQt in 8,388,608..13,631,488 (all dead pre-stage-9)
//   ckv_b u16 @ 16,777,216 | kvgb u16 @ 20,971,520 | vt u16 @ 37,748,736
//   qb u16 @ 46,137,344 | WdKVt u16 @ 48,234,496 | Wukvt u16 @ 49,283,072

typedef __attribute__((ext_vector_type(8))) short short8;
typedef __attribute__((ext_vector_type(4))) float f32x4;

__device__ __forceinline__ ushort f2bf(float x) {
    __hip_bfloat16 h = __float2bfloat16(x);
    return *reinterpret_cast<ushort*>(&h);
}

// XOR swizzle in units of shorts: permutes 8-short (16B) blocks within each
// 64-short (128B) stripe by the low 3 row bits. Bijective per row; keeps
// 16B alignment for any col that is a multiple of 8.
#define SWZ(row, col) ((col) ^ (((row) & 7) << 3))

// ---------- elementwise fp32 -> bf16 cast, 8 elems/thread (VERIFIED r6)
__global__ __launch_bounds__(256) void cast_bf16(const float* __restrict__ src,
        ushort* __restrict__ dst)
{
    size_t i = ((size_t)blockIdx.x * 256 + threadIdx.x) * 8;
    float4 a = *(const float4*)(src + i);
    float4 b = *(const float4*)(src + i + 4);
    ushort u[8] = {f2bf(a.x), f2bf(a.y), f2bf(a.z), f2bf(a.w),
                   f2bf(b.x), f2bf(b.y), f2bf(b.z), f2bf(b.w)};
    *(uint4*)(dst + i) = *(uint4*)u;
}

// ---------- transpose + cast (VERIFIED r6)
__global__ __launch_bounds__(256) void transpose_cast(const float* __restrict__ src,
        ushort* __restrict__ dst, int srl, int dstld, int remap,
        long src_z, long dst_z)
{
    __shared__ ushort tile[64][68];
    const int k0 = blockIdx.x * 64;
    const int n0 = blockIdx.y * 64;
    src += (size_t)blockIdx.z * src_z;
    dst += (size_t)blockIdx.z * dst_z;
    const int cb = n0 + (remap ? (n0 >> 7) * 64 : 0);
    const int t = threadIdx.x;
    {
        int r = t >> 4, c4 = t & 15;
        #pragma unroll
        for (int i = 0; i < 4; ++i) {
            float4 v = *(const float4*)(src + (size_t)(k0 + r + 16 * i) * srl + cb + c4 * 4);
            tile[r + 16 * i][c4 * 4 + 0] = f2bf(v.x);
            tile[r + 16 * i][c4 * 4 + 1] = f2bf(v.y);
            tile[r + 16 * i][c4 * 4 + 2] = f2bf(v.z);
            tile[r + 16 * i][c4 * 4 + 3] = f2bf(v.w);
        }
    }
    __syncthreads();
    {
        int n = t >> 4, k4 = t & 15;
        #pragma unroll
        for (int i = 0; i < 4; ++i) {
            ushort4 v;
            v.x = tile[k4 * 4 + 0][n + 16 * i];
            v.y = tile[k4 * 4 + 1][n + 16 * i];
            v.z = tile[k4 * 4 + 2][n + 16 * i];
            v.w = tile[k4 * 4 + 3][n + 16 * i];
            *(ushort4*)(dst + (size_t)(n0 + n + 16 * i) * dstld + k0 + k4 * 4) = v;
        }
    }
}

// ---------- MFMA bf16 GEMM (VERIFIED r6)
__global__ __launch_bounds__(256) void gemm_mfma(const ushort* __restrict__ A,
        const ushort* __restrict__ Bt, void* __restrict__ Cv,
        int M, int N, int K, int lda, int ldb, int ldc, int obf16, float scale)
{
    __shared__ ushort As[128][72];
    __shared__ ushort Bs[128][72];
    const int tid = threadIdx.x;
    const int w = tid >> 6, lane = tid & 63;
    const int quad = lane >> 4, l16 = lane & 15;
    const int wm = (w >> 1) * 64, wn = (w & 1) * 64;
    const int m0 = blockIdx.y * 128, n0 = blockIdx.x * 128;

    f32x4 acc[4][4];
    #pragma unroll
    for (int i = 0; i < 4; ++i)
        #pragma unroll
        for (int j = 0; j < 4; ++j) acc[i][j] = (f32x4){0.f, 0.f, 0.f, 0.f};

    const int str = tid >> 3;
    const int stc = (tid & 7) * 8;

    for (int k0 = 0; k0 < K; k0 += 64) {
        __syncthreads();
        #pragma unroll
        for (int i = 0; i < 4; ++i) {
            int r = str + 32 * i;
            *(uint4*)&As[r][stc] = *(const uint4*)(A + (size_t)(m0 + r) * lda + k0 + stc);
            *(uint4*)&Bs[r][stc] = *(const uint4*)(Bt + (size_t)(n0 + r) * ldb + k0 + stc);
        }
        __syncthreads();
        #pragma unroll
        for (int kc = 0; kc < 2; ++kc) {
            short8 af[4], bf[4];
            #pragma unroll
            for (int i = 0; i < 4; ++i) {
                af[i] = *(const short8*)&As[wm + i * 16 + l16][kc * 32 + quad * 8];
                bf[i] = *(const short8*)&Bs[wn + i * 16 + l16][kc * 32 + quad * 8];
            }
            #pragma unroll
            for (int i = 0; i < 4; ++i)
                #pragma unroll
                for (int j = 0; j < 4; ++j)
                    acc[i][j] = __builtin_amdgcn_mfma_f32_16x16x32_bf16(af[i], bf[j], acc[i][j], 0, 0, 0);
        }
    }
    if (!obf16) {
        float* C = (float*)Cv;
        #pragma unroll
        for (int i = 0; i < 4; ++i)
            #pragma unroll
            for (int r = 0; r < 4; ++r) {
                float* cp = C + (size_t)(m0 + wm + i * 16 + quad * 4 + r) * ldc + n0 + wn + l16;
                #pragma unroll
                for (int j = 0; j < 4; ++j) cp[j * 16] = acc[i][j][r] * scale;
            }
    } else {
        ushort* C = (ushort*)Cv;
        #pragma unroll
        for (int i = 0; i < 4; ++i)
            #pragma unroll
            for (int r = 0; r < 4; ++r) {
                ushort* cp = C + (size_t)(m0 + wm + i * 16 + quad * 4 + r) * ldc + n0 + wn + l16;
                #pragma unroll
                for (int j = 0; j < 4; ++j) cp[j * 16] = f2bf(acc[i][j][r] * scale);
            }
    }
}

// ---------- coalesced rmsnorm, 512 cols, wave per row, bf16 out (VERIFIED r7)
__global__ __launch_bounds__(256) void rms_q_wave(const float* __restrict__ x,
        const float* __restrict__ w, ushort* __restrict__ dst)
{
    const int row = blockIdx.x * 4 + (threadIdx.x >> 6);
    const int lane = threadIdx.x & 63;
    const float* p = x + (size_t)row * 512;
    float4 v0 = *(const float4*)(p + lane * 4);
    float4 v1 = *(const float4*)(p + 256 + lane * 4);
    float ss = v0.x*v0.x + v0.y*v0.y + v0.z*v0.z + v0.w*v0.w
             + v1.x*v1.x + v1.y*v1.y + v1.z*v1.z + v1.w*v1.w;
    #pragma unroll
    for (int m = 1; m < 64; m <<= 1) ss += __shfl_xor(ss, m);
    float inv = rsqrtf(ss * (1.f / 512.f) + 1e-6f);
    float4 w0 = *(const float4*)(w + lane * 4);
    float4 w1 = *(const float4*)(w + 256 + lane * 4);
    ushort* dp = dst + (size_t)row * 512;
    ushort4 o0, o1;
    o0.x = f2bf(v0.x * inv * w0.x); o0.y = f2bf(v0.y * inv * w0.y);
    o0.z = f2bf(v0.z * inv * w0.z); o0.w = f2bf(v0.w * inv * w0.w);
    o1.x = f2bf(v1.x * inv * w1.x); o1.y = f2bf(v1.y * inv * w1.y);
    o1.z = f2bf(v1.z * inv * w1.z); o1.w = f2bf(v1.w * inv * w1.w);
    *(ushort4*)(dp + lane * 4)       = o0;
    *(ushort4*)(dp + 256 + lane * 4) = o1;
}

// ---------- coalesced grouped rmsnorm, 256 cols/group, wave per (row,g) (VERIFIED r7)
__global__ __launch_bounds__(256) void rms_kv_wave(const float* __restrict__ x,
        const float* __restrict__ w, ushort* __restrict__ dst)
{
    const int idx = blockIdx.x * 4 + (threadIdx.x >> 6);   // 0..32767
    const int lane = threadIdx.x & 63;
    const int r = idx >> 2, g = idx & 3;
    const float* p = x + (size_t)r * 1024 + g * 256;
    float4 v = *(const float4*)(p + lane * 4);
    float ss = v.x*v.x + v.y*v.y + v.z*v.z + v.w*v.w;
    #pragma unroll
    for (int m = 1; m < 64; m <<= 1) ss += __shfl_xor(ss, m);
    float inv = rsqrtf(ss * (1.f / 256.f) + 1e-6f);
    float4 wv = *(const float4*)(w + g * 256 + lane * 4);
    ushort4 o;
    o.x = f2bf(v.x * inv * wv.x); o.y = f2bf(v.y * inv * wv.y);
    o.z = f2bf(v.z * inv * wv.z); o.w = f2bf(v.w * inv * wv.w);
    *(ushort4*)(dst + (size_t)r * 1024 + g * 256 + lane * 4) = o;
}

// ---------- V transpose (VERIFIED r5/r6)
__global__ __launch_bounds__(256) void transpose_v(const ushort* __restrict__ KVb,
                                                   ushort* __restrict__ Vt)
{
    __shared__ ushort tile[64][66];
    const int s0 = blockIdx.x * 64;
    const int d0 = blockIdx.y * 64;
    const int bh = blockIdx.z;
    const int b = bh >> 4, h = bh & 15, g = h >> 2, p = h & 3;
    const int t = threadIdx.x;
    const ushort* src = KVb + (size_t)g * 8388608ull + (size_t)(b * 4096) * 1024 + p * 256 + 128;
    {
        int sl = t >> 4, c4 = t & 15;
        #pragma unroll
        for (int i = 0; i < 4; ++i) {
            int s = sl + 16 * i;
            ushort4 v = *(const ushort4*)(src + (size_t)(s0 + s) * 1024 + d0 + c4 * 4);
            tile[s][c4 * 4 + 0] = v.x; tile[s][c4 * 4 + 1] = v.y;
            tile[s][c4 * 4 + 2] = v.z; tile[s][c4 * 4 + 3] = v.w;
        }
    }
    __syncthreads();
    {
        int dl = t >> 4, s4 = t & 15;
        ushort* dst = Vt + (size_t)(b * 16 + h) * 128 * 4096;
        #pragma unroll
        for (int i = 0; i < 4; ++i) {
            int d = dl + 16 * i;
            ushort4 v;
            v.x = tile[s4 * 4 + 0][d]; v.y = tile[s4 * 4 + 1][d];
            v.z = tile[s4 * 4 + 2][d]; v.w = tile[s4 * 4 + 3][d];
            *(ushort4*)(dst + (size_t)(d0 + d) * 4096 + s0 + s4 * 4) = v;
        }
    }
}

// ---------- MFMA flash attention, SPLIT-s=2, round-8 rework.
// grid (16, 16, 4): z = b*2 + chunk; chunk covers s in [chunk*2048, +2048).
// Writes UNNORMALIZED fp32 O partials + per-row (m,l) for the merge pass.
// LDS = 40960 B exactly (4 blocks/CU); XOR-swizzled tiles; reg-prefetched K/V;
// 2 barriers/iter (Ps is wave-private); defer-max rescale (THR=8).
__global__ __launch_bounds__(256, 4) void attn_mfma_split(const ushort* __restrict__ Qb,
        const ushort* __restrict__ KVb, const ushort* __restrict__ Vt,
        float* __restrict__ Opart, float* __restrict__ ml)
{
    __shared__ ushort Ks[64 * 128];      // 16384 B, swizzled rows of 128 shorts
    __shared__ ushort VsT[128 * 64];     // 16384 B, swizzled rows of 64 shorts
    __shared__ ushort Ps[4 * 16 * 64];   //  8192 B, per-wave 16x64, swizzled

    const int q0 = blockIdx.x * 64;
    const int h = blockIdx.y;
    const int b = blockIdx.z >> 1, chunk = blockIdx.z & 1;
    const int g = h >> 2, p = h & 3;
    const int tid = threadIdx.x;
    const int w = tid >> 6, lane = tid & 63;
    const int quad = lane >> 4, l16 = lane & 15;
    const int sbase = chunk * 2048;

    const ushort* qg = Qb + (size_t)(b * 1024 + q0) * 2048 + h * 128;
    const ushort* kg = KVb + (size_t)g * 8388608ull + (size_t)(b * 4096 + sbase) * 1024 + p * 256;
    const ushort* vg = Vt + (size_t)(b * 16 + h) * 128 * 4096 + sbase;

    const int kr  = tid >> 4;            // K/Q staging: rows kr+16i, col kc8 (shorts)
    const int kc8 = (tid & 15) * 8;
    const int vd  = tid >> 3;            // V staging: rows vd+32i, col vs8 (shorts)
    const int vs8 = (tid & 7) * 8;

    // issue tile-0 K/V loads early; they drain while Q is staged/read
    uint4 krg[4], vrg[4];
    #pragma unroll
    for (int i = 0; i < 4; ++i)
        krg[i] = *(const uint4*)(kg + (size_t)(kr + 16 * i) * 1024 + kc8);
    #pragma unroll
    for (int i = 0; i < 4; ++i)
        vrg[i] = *(const uint4*)(vg + (size_t)(vd + 32 * i) * 4096 + vs8);

    // stage Q through Ks (swizzled), pull per-lane fragments
    #pragma unroll
    for (int i = 0; i < 4; ++i) {
        int r = kr + 16 * i;
        *(uint4*)&Ks[r * 128 + SWZ(r, kc8)] = *(const uint4*)(qg + (size_t)r * 2048 + kc8);
    }
    __syncthreads();
    short8 qf[4];
    {
        int qr = w * 16 + l16;
        #pragma unroll
        for (int kc = 0; kc < 4; ++kc)
            qf[kc] = *(const short8*)&Ks[qr * 128 + SWZ(qr, kc * 32 + quad * 8)];
    }

    f32x4 accO[8];
    float m_i[4], l_i[4];
    #pragma unroll
    for (int dt = 0; dt < 8; ++dt) accO[dt] = (f32x4){0.f, 0.f, 0.f, 0.f};
    #pragma unroll
    for (int r = 0; r < 4; ++r) { m_i[r] = -INFINITY; l_i[r] = 0.f; }

    for (int s0 = 0; s0 < 2048; s0 += 64) {
        __syncthreads();                               // all waves done reading tiles
        #pragma unroll
        for (int i = 0; i < 4; ++i) {
            int r = kr + 16 * i;
            *(uint4*)&Ks[r * 128 + SWZ(r, kc8)] = krg[i];
        }
        #pragma unroll
        for (int i = 0; i < 4; ++i) {
            int d = vd + 32 * i;
            *(uint4*)&VsT[d * 64 + SWZ(d, vs8)] = vrg[i];
        }
        __syncthreads();
        if (s0 + 64 < 2048) {                          // prefetch next tile into regs;
            #pragma unroll                             // latency hides under compute below
            for (int i = 0; i < 4; ++i)
                krg[i] = *(const uint4*)(kg + (size_t)(s0 + 64 + kr + 16 * i) * 1024 + kc8);
            #pragma unroll
            for (int i = 0; i < 4; ++i)
                vrg[i] = *(const uint4*)(vg + (size_t)(vd + 32 * i) * 4096 + s0 + 64 + vs8);
        }
        // QK^T
        f32x4 accS[4];
        #pragma unroll
        for (int st = 0; st < 4; ++st) accS[st] = (f32x4){0.f, 0.f, 0.f, 0.f};
        #pragma unroll
        for (int kc = 0; kc < 4; ++kc) {
            #pragma unroll
            for (int st = 0; st < 4; ++st) {
                int krow = st * 16 + l16;
                short8 kf = *(const short8*)&Ks[krow * 128 + SWZ(krow, kc * 32 + quad * 8)];
                accS[st] = __builtin_amdgcn_mfma_f32_16x16x32_bf16(qf[kc], kf, accS[st], 0, 0, 0);
            }
        }
        // online softmax, defer-max (THR=8): P bounded by e^8, fp32 accum safe
        #pragma unroll
        for (int r = 0; r < 4; ++r) {
            float tm = fmaxf(fmaxf(accS[0][r], accS[1][r]), fmaxf(accS[2][r], accS[3][r]));
            #pragma unroll
            for (int msk = 1; msk < 16; msk <<= 1) tm = fmaxf(tm, __shfl_xor(tm, msk));
            if (tm > m_i[r] + 8.f) {                   // uniform within 16-lane group
                float alpha = __expf(m_i[r] - tm);
                l_i[r] *= alpha;
                #pragma unroll
                for (int dt = 0; dt < 8; ++dt) accO[dt][r] *= alpha;
                m_i[r] = tm;
            }
            const float mn = m_i[r];
            float rs = 0.f;
            const int prow = quad * 4 + r;
            #pragma unroll
            for (int st = 0; st < 4; ++st) {
                float e = __expf(accS[st][r] - mn);
                rs += e;
                Ps[(w * 16 + prow) * 64 + SWZ(prow, st * 16 + l16)] = f2bf(e);
            }
            #pragma unroll
            for (int msk = 1; msk < 16; msk <<= 1) rs += __shfl_xor(rs, msk);
            l_i[r] += rs;
        }
        // Ps is wave-private: no block barrier; intra-wave lgkmcnt orders write->read
        short8 pf[2];
        #pragma unroll
        for (int sc = 0; sc < 2; ++sc)
            pf[sc] = *(const short8*)&Ps[(w * 16 + l16) * 64 + SWZ(l16, sc * 32 + quad * 8)];
        #pragma unroll
        for (int sc = 0; sc < 2; ++sc) {
            #pragma unroll
            for (int dt = 0; dt < 8; ++dt) {
                int vrow = dt * 16 + l16;
                short8 vf = *(const short8*)&VsT[vrow * 64 + SWZ(vrow, sc * 32 + quad * 8)];
                accO[dt] = __builtin_amdgcn_mfma_f32_16x16x32_bf16(pf[sc], vf, accO[dt], 0, 0, 0);
            }
        }
    }
    // epilogue: unnormalized fp32 partials + (m,l)
    const int qrow = q0 + w * 16 + quad * 4;
    float* ob = Opart + (size_t)((chunk * 2 + b) * 1024 + qrow) * 2048 + h * 128 + l16;
    #pragma unroll
    for (int r = 0; r < 4; ++r)
        #pragma unroll
        for (int dt = 0; dt < 8; ++dt)
            ob[(size_t)r * 2048 + dt * 16] = accO[dt][r];
    if (l16 == 0) {
        #pragma unroll
        for (int r = 0; r < 4; ++r) {
            size_t mi = ((size_t)((chunk * 2 + b) * 1024 + qrow + r) * 16 + h) * 2;
            ml[mi] = m_i[r];
            ml[mi + 1] = l_i[r];
        }
    }
}

// ---------- merge the 2 s-chunks: one wave per (b,q,h); lane owns d=lane, lane+64
__global__ __launch_bounds__(256) void attn_merge(const float* __restrict__ Opart,
        const float* __restrict__ ml, ushort* __restrict__ Om)
{
    const int idx = blockIdx.x * 4 + (threadIdx.x >> 6);  // 0..32767
    const int lane = threadIdx.x & 63;
    const int h = idx & 15;
    const int q = (idx >> 4) & 1023;
    const int b = idx >> 14;

    size_t m1i = ((size_t)((0 * 2 + b) * 1024 + q) * 16 + h) * 2;
    size_t m2i = ((size_t)((1 * 2 + b) * 1024 + q) * 16 + h) * 2;
    float m1 = ml[m1i], l1 = ml[m1i + 1];
    float m2 = ml[m2i], l2 = ml[m2i + 1];
    float M = fmaxf(m1, m2);
    float w1 = __expf(m1 - M), w2 = __expf(m2 - M);
    float invL = 1.f / (l1 * w1 + l2 * w2);

    const float* o1 = Opart + (size_t)((0 * 2 + b) * 1024 + q) * 2048 + h * 128;
    const float* o2 = Opart + (size_t)((1 * 2 + b) * 1024 + q) * 2048 + h * 128;
    ushort* ob = Om + (size_t)(b * 1024 + q) * 2048 + h * 128;
    ob[lane]      = f2bf((o1[lane]      * w1 + o2[lane]      * w2) * invL);
    ob[lane + 64] = f2bf((o1[lane + 64] * w1 + o2[lane + 64] * w2) * invL);
}

extern "C" void kernel_launch(void* const* d_in, const int* in_sizes, int n_in,
                              void* d_out, int out_size, void* d_ws, size_t ws_size,
                              hipStream_t stream)
{
    (void)in_sizes; (void)n_in; (void)out_size; (void)ws_size;
    const float* x_q       = (const float*)d_in[0];
    const float* x_kv      = (const float*)d_in[1];
    const float* W_dQ      = (const float*)d_in[2];
    const float* q_norm_w  = (const float*)d_in[3];
    const float* W_uQ      = (const float*)d_in[4];
    const float* W_dKV     = (const float*)d_in[5];
    const float* kv_norm_w = (const float*)d_in[6];
    const float* W_ukv     = (const float*)d_in[7];
    const float* W_o       = (const float*)d_in[8];
    float* out = (float*)d_out;

    float* ws = (float*)d_ws;
    ushort* xkvb       = (ushort*)ws;
    ushort* attn_out_b = (ushort*)ws;
    float*  mlbuf      = ws + 2097152ull;
    ushort* Wot        = (ushort*)(ws + 4194304ull);
    float*  ckv        = ws + 8388608ull;
    float*  Opart      = ws + 8388608ull;                 // aliases dead ckv
    ushort* xqb        = (ushort*)(ws + 8388608ull);      // pre-stage-9 only
    ushort* WdQt       = (ushort*)(ws + 10485760ull);
    float*  q_lat      = ws + 11010048ull;
    ushort* q_lat_b    = (ushort*)(ws + 12058624ull);
    ushort* WuQt       = (ushort*)(ws + 12582912ull);
    ushort* ckv_b      = (ushort*)(ws + 16777216ull);
    ushort* kvgb       = (ushort*)(ws + 20971520ull);
    ushort* vt         = (ushort*)(ws + 37748736ull);
    ushort* qb         = (ushort*)(ws + 46137344ull);
    ushort* WdKVt      = (ushort*)(ws + 48234496ull);
    ushort* Wukvt      = (ushort*)(ws + 49283072ull);

    const float qscale = 0.08838834764831845f;            // 1/sqrt(128)

    // 1-3) q_lat = bf16(x_q) @ bf16(W_dQ)
    cast_bf16<<<2048, 256, 0, stream>>>(x_q, xqb);
    transpose_cast<<<dim3(32, 8, 1), 256, 0, stream>>>(W_dQ, WdQt, 512, 2048, 0, 0, 0);
    gemm_mfma<<<dim3(4, 16), 256, 0, stream>>>(xqb, WdQt, q_lat, 2048, 512, 2048, 2048, 2048, 512, 0, 1.f);
    // 4) rmsnorm -> bf16 (coalesced)
    rms_q_wave<<<512, 256, 0, stream>>>(q_lat, q_norm_w, q_lat_b);
    // 5-6) qb = (q_lat_b @ W_uQ[:, head :128]) * qscale
    transpose_cast<<<dim3(8, 32, 1), 256, 0, stream>>>(W_uQ, WuQt, 3072, 512, 1, 0, 0);
    gemm_mfma<<<dim3(16, 16), 256, 0, stream>>>(q_lat_b, WuQt, qb, 2048, 2048, 512, 512, 512, 2048, 1, qscale);
    // 7-9) ckv = bf16(x_kv) @ bf16(W_dKV[:, :1024])
    cast_bf16<<<8192, 256, 0, stream>>>(x_kv, xkvb);
    transpose_cast<<<dim3(32, 16, 1), 256, 0, stream>>>(W_dKV, WdKVt, 1088, 2048, 0, 0, 0);
    gemm_mfma<<<dim3(8, 64), 256, 0, stream>>>(xkvb, WdKVt, ckv, 8192, 1024, 2048, 2048, 2048, 1024, 0, 1.f);
    // 10) grouped rmsnorm -> bf16 (coalesced)
    rms_kv_wave<<<8192, 256, 0, stream>>>(ckv, kv_norm_w, ckv_b);
    // 11-12) kv up-projection per group -> bf16 kvgb
    transpose_cast<<<dim3(4, 16, 4), 256, 0, stream>>>(W_ukv, Wukvt, 1024, 256, 0, 262144, 262144);
    for (int g = 0; g < 4; ++g)
        gemm_mfma<<<dim3(8, 64), 256, 0, stream>>>(ckv_b + g * 256, Wukvt + (size_t)g * 262144,
                                                   kvgb + (size_t)g * 8388608ull,
                                                   8192, 1024, 256, 1024, 256, 1024, 1, 1.f);
    // 13) V transpose
    transpose_v<<<dim3(64, 2, 32), 256, 0, stream>>>(kvgb, vt);
    // 14) split-s MFMA flash attention + merge
    attn_mfma_split<<<dim3(16, 16, 4), 256, 0, stream>>>(qb, kvgb, vt, Opart, mlbuf);
    attn_merge<<<8192, 256, 0, stream>>>(Opart, mlbuf, attn_out_b);
    // 15-16) out = attn_out_b @ bf16(W_o)
    transpose_cast<<<dim3(32, 32, 1), 256, 0, stream>>>(W_o, Wot, 2048, 2048, 0, 0, 0);
    gemm_mfma<<<dim3(16, 16), 256, 0, stream>>>(attn_out_b, Wot, out, 2048, 2048, 2048, 2048, 2048, 2048, 0, 1.f);
}

// Round 2
// 558.376 us; speedup vs baseline: 1.3757x; 1.3757x over previous
//
#include <hip/hip_runtime.h>
#include <hip/hip_bf16.h>
#include <math.h>

// GLA cross-attention — round 9:
//  r8 post-mortem: forced __launch_bounds__(256,4) + 32 reg-prefetch VGPRs
//  caused inner-loop scratch spills (WRITE_SIZE 33MB -> 1.08GB) — kernel went
//  spill-BW-bound. r9 removes register pressure instead of capping it:
//   (a) K/V staging via __builtin_amdgcn_global_load_lds width=16 with
//       PRE-SWIZZLED per-lane global source (LDS dest linear, m173 pattern).
//       No prefetch regs, no ds_write VALU, no spills possible.
//   (b) keep: XOR-swizzled 40960B LDS (4 blocks/CU), 2 barriers/iter
//       (Ps wave-private), defer-max (THR=8) — all verified passing in r8.
//   (c) plain __launch_bounds__(256): occupancy from LDS + natural VGPR.
//   (d) same gload_lds+swizzle transform applied to gemm_mfma (m93->m97
//       ladder step): unpadded 128x64 tiles, 32KB LDS.
//
// ws float-offset map (alias notes; top = 49,807,360 f = 199.2 MB):
//   attn_out_b u16 @ 0          (4,194,304 u -> 2,097,152 f)
//   ml        f32 @ 2,097,152   (131,072 f)   [attn stage only; gap before Wot]
//   Wot       u16 @ f4,194,304  (4,194,304 u) [stage 15+]
//   xkvb      u16 @ 0           dead after stage 9
//   ckv       f32 @ 8,388,608   dead after stage 10
//   Opart     f32 @ 8,388,608   [attn stage; aliases dead ckv]
//   xqb/WdQt/q_lat/q_lat_b/WuQt in 8,388,608..13,631,488 (dead pre-stage-9)
//   ckv_b u16 @ 16,777,216 | kvgb u16 @ 20,971,520 | vt u16 @ 37,748,736
//   qb u16 @ 46,137,344 | WdKVt u16 @ 48,234,496 | Wukvt u16 @ 49,283,072

typedef __attribute__((ext_vector_type(8))) short short8;
typedef __attribute__((ext_vector_type(4))) float f32x4;

__device__ __forceinline__ ushort f2bf(float x) {
    __hip_bfloat16 h = __float2bfloat16(x);
    return *reinterpret_cast<ushort*>(&h);
}

// XOR swizzle in units of shorts: permutes 8-short (16B) blocks within each
// 64/128-short row by the low 3 row bits. Bijective; keeps 16B alignment.
#define SWZ(row, col) ((col) ^ (((row) & 7) << 3))

// async global->LDS, 16B per lane. LDS dest = wave-uniform base + lane*16
// (linear); global src is per-lane (carries the swizzle). Drained by the
// compiler's vmcnt(0) before the next __syncthreads().
__device__ __forceinline__ void gload16(const ushort* g, ushort* l)
{
    __builtin_amdgcn_global_load_lds(
        (const __attribute__((address_space(1))) void*)g,
        (__attribute__((address_space(3))) void*)l, 16, 0, 0);
}

// ---------- elementwise fp32 -> bf16 cast, 8 elems/thread (VERIFIED r6)
__global__ __launch_bounds__(256) void cast_bf16(const float* __restrict__ src,
        ushort* __restrict__ dst)
{
    size_t i = ((size_t)blockIdx.x * 256 + threadIdx.x) * 8;
    float4 a = *(const float4*)(src + i);
    float4 b = *(const float4*)(src + i + 4);
    ushort u[8] = {f2bf(a.x), f2bf(a.y), f2bf(a.z), f2bf(a.w),
                   f2bf(b.x), f2bf(b.y), f2bf(b.z), f2bf(b.w)};
    *(uint4*)(dst + i) = *(uint4*)u;
}

// ---------- transpose + cast (VERIFIED r6)
__global__ __launch_bounds__(256) void transpose_cast(const float* __restrict__ src,
        ushort* __restrict__ dst, int srl, int dstld, int remap,
        long src_z, long dst_z)
{
    __shared__ ushort tile[64][68];
    const int k0 = blockIdx.x * 64;
    const int n0 = blockIdx.y * 64;
    src += (size_t)blockIdx.z * src_z;
    dst += (size_t)blockIdx.z * dst_z;
    const int cb = n0 + (remap ? (n0 >> 7) * 64 : 0);
    const int t = threadIdx.x;
    {
        int r = t >> 4, c4 = t & 15;
        #pragma unroll
        for (int i = 0; i < 4; ++i) {
            float4 v = *(const float4*)(src + (size_t)(k0 + r + 16 * i) * srl + cb + c4 * 4);
            tile[r + 16 * i][c4 * 4 + 0] = f2bf(v.x);
            tile[r + 16 * i][c4 * 4 + 1] = f2bf(v.y);
            tile[r + 16 * i][c4 * 4 + 2] = f2bf(v.z);
            tile[r + 16 * i][c4 * 4 + 3] = f2bf(v.w);
        }
    }
    __syncthreads();
    {
        int n = t >> 4, k4 = t & 15;
        #pragma unroll
        for (int i = 0; i < 4; ++i) {
            ushort4 v;
            v.x = tile[k4 * 4 + 0][n + 16 * i];
            v.y = tile[k4 * 4 + 1][n + 16 * i];
            v.z = tile[k4 * 4 + 2][n + 16 * i];
            v.w = tile[k4 * 4 + 3][n + 16 * i];
            *(ushort4*)(dst + (size_t)(n0 + n + 16 * i) * dstld + k0 + k4 * 4) = v;
        }
    }
}

// ---------- MFMA bf16 GEMM — r9: gload_lds staging, swizzled 128x64 tiles
__global__ __launch_bounds__(256) void gemm_mfma(const ushort* __restrict__ A,
        const ushort* __restrict__ Bt, void* __restrict__ Cv,
        int M, int N, int K, int lda, int ldb, int ldc, int obf16, float scale)
{
    __shared__ ushort As[128 * 64];
    __shared__ ushort Bs[128 * 64];
    const int tid = threadIdx.x;
    const int w = tid >> 6, lane = tid & 63;
    const int quad = lane >> 4, l16 = lane & 15;
    const int wm = (w >> 1) * 64, wn = (w & 1) * 64;
    const int m0 = blockIdx.y * 128, n0 = blockIdx.x * 128;

    f32x4 acc[4][4];
    #pragma unroll
    for (int i = 0; i < 4; ++i)
        #pragma unroll
        for (int j = 0; j < 4; ++j) acc[i][j] = (f32x4){0.f, 0.f, 0.f, 0.f};

    // staging geometry: wave w covers rows w*32..w*32+31; issue i covers 8 rows.
    // per-lane: row = w*32 + i*8 + (lane>>3), swizzled src col.
    const int srow = lane >> 3;
    const int scol = ((lane & 7) * 8) ^ ((srow & 7) << 3);   // (row&7)==srow&7

    for (int k0 = 0; k0 < K; k0 += 64) {
        __syncthreads();
        #pragma unroll
        for (int i = 0; i < 4; ++i) {
            int r = w * 32 + i * 8 + srow;
            gload16(A + (size_t)(m0 + r) * lda + k0 + scol, &As[w * 2048 + i * 512]);
            gload16(Bt + (size_t)(n0 + r) * ldb + k0 + scol, &Bs[w * 2048 + i * 512]);
        }
        __syncthreads();
        #pragma unroll
        for (int kc = 0; kc < 2; ++kc) {
            short8 af[4], bf[4];
            #pragma unroll
            for (int i = 0; i < 4; ++i) {
                int ra = wm + i * 16 + l16;
                int rb = wn + i * 16 + l16;
                af[i] = *(const short8*)&As[ra * 64 + SWZ(ra, kc * 32 + quad * 8)];
                bf[i] = *(const short8*)&Bs[rb * 64 + SWZ(rb, kc * 32 + quad * 8)];
            }
            #pragma unroll
            for (int i = 0; i < 4; ++i)
                #pragma unroll
                for (int j = 0; j < 4; ++j)
                    acc[i][j] = __builtin_amdgcn_mfma_f32_16x16x32_bf16(af[i], bf[j], acc[i][j], 0, 0, 0);
        }
    }
    if (!obf16) {
        float* C = (float*)Cv;
        #pragma unroll
        for (int i = 0; i < 4; ++i)
            #pragma unroll
            for (int r = 0; r < 4; ++r) {
                float* cp = C + (size_t)(m0 + wm + i * 16 + quad * 4 + r) * ldc + n0 + wn + l16;
                #pragma unroll
                for (int j = 0; j < 4; ++j) cp[j * 16] = acc[i][j][r] * scale;
            }
    } else {
        ushort* C = (ushort*)Cv;
        #pragma unroll
        for (int i = 0; i < 4; ++i)
            #pragma unroll
            for (int r = 0; r < 4; ++r) {
                ushort* cp = C + (size_t)(m0 + wm + i * 16 + quad * 4 + r) * ldc + n0 + wn + l16;
                #pragma unroll
                for (int j = 0; j < 4; ++j) cp[j * 16] = f2bf(acc[i][j][r] * scale);
            }
    }
}

// ---------- coalesced rmsnorm, 512 cols, wave per row, bf16 out (VERIFIED r7)
__global__ __launch_bounds__(256) void rms_q_wave(const float* __restrict__ x,
        const float* __restrict__ w, ushort* __restrict__ dst)
{
    const int row = blockIdx.x * 4 + (threadIdx.x >> 6);
    const int lane = threadIdx.x & 63;
    const float* p = x + (size_t)row * 512;
    float4 v0 = *(const float4*)(p + lane * 4);
    float4 v1 = *(const float4*)(p + 256 + lane * 4);
    float ss = v0.x*v0.x + v0.y*v0.y + v0.z*v0.z + v0.w*v0.w
             + v1.x*v1.x + v1.y*v1.y + v1.z*v1.z + v1.w*v1.w;
    #pragma unroll
    for (int m = 1; m < 64; m <<= 1) ss += __shfl_xor(ss, m);
    float inv = rsqrtf(ss * (1.f / 512.f) + 1e-6f);
    float4 w0 = *(const float4*)(w + lane * 4);
    float4 w1 = *(const float4*)(w + 256 + lane * 4);
    ushort* dp = dst + (size_t)row * 512;
    ushort4 o0, o1;
    o0.x = f2bf(v0.x * inv * w0.x); o0.y = f2bf(v0.y * inv * w0.y);
    o0.z = f2bf(v0.z * inv * w0.z); o0.w = f2bf(v0.w * inv * w0.w);
    o1.x = f2bf(v1.x * inv * w1.x); o1.y = f2bf(v1.y * inv * w1.y);
    o1.z = f2bf(v1.z * inv * w1.z); o1.w = f2bf(v1.w * inv * w1.w);
    *(ushort4*)(dp + lane * 4)       = o0;
    *(ushort4*)(dp + 256 + lane * 4) = o1;
}

// ---------- coalesced grouped rmsnorm, 256 cols/group, wave per (row,g) (VERIFIED r7)
__global__ __launch_bounds__(256) void rms_kv_wave(const float* __restrict__ x,
        const float* __restrict__ w, ushort* __restrict__ dst)
{
    const int idx = blockIdx.x * 4 + (threadIdx.x >> 6);   // 0..32767
    const int lane = threadIdx.x & 63;
    const int r = idx >> 2, g = idx & 3;
    const float* p = x + (size_t)r * 1024 + g * 256;
    float4 v = *(const float4*)(p + lane * 4);
    float ss = v.x*v.x + v.y*v.y + v.z*v.z + v.w*v.w;
    #pragma unroll
    for (int m = 1; m < 64; m <<= 1) ss += __shfl_xor(ss, m);
    float inv = rsqrtf(ss * (1.f / 256.f) + 1e-6f);
    float4 wv = *(const float4*)(w + g * 256 + lane * 4);
    ushort4 o;
    o.x = f2bf(v.x * inv * wv.x); o.y = f2bf(v.y * inv * wv.y);
    o.z = f2bf(v.z * inv * wv.z); o.w = f2bf(v.w * inv * wv.w);
    *(ushort4*)(dst + (size_t)r * 1024 + g * 256 + lane * 4) = o;
}

// ---------- V transpose (VERIFIED r5/r6)
__global__ __launch_bounds__(256) void transpose_v(const ushort* __restrict__ KVb,
                                                   ushort* __restrict__ Vt)
{
    __shared__ ushort tile[64][66];
    const int s0 = blockIdx.x * 64;
    const int d0 = blockIdx.y * 64;
    const int bh = blockIdx.z;
    const int b = bh >> 4, h = bh & 15, g = h >> 2, p = h & 3;
    const int t = threadIdx.x;
    const ushort* src = KVb + (size_t)g * 8388608ull + (size_t)(b * 4096) * 1024 + p * 256 + 128;
    {
        int sl = t >> 4, c4 = t & 15;
        #pragma unroll
        for (int i = 0; i < 4; ++i) {
            int s = sl + 16 * i;
            ushort4 v = *(const ushort4*)(src + (size_t)(s0 + s) * 1024 + d0 + c4 * 4);
            tile[s][c4 * 4 + 0] = v.x; tile[s][c4 * 4 + 1] = v.y;
            tile[s][c4 * 4 + 2] = v.z; tile[s][c4 * 4 + 3] = v.w;
        }
    }
    __syncthreads();
    {
        int dl = t >> 4, s4 = t & 15;
        ushort* dst = Vt + (size_t)(b * 16 + h) * 128 * 4096;
        #pragma unroll
        for (int i = 0; i < 4; ++i) {
            int d = dl + 16 * i;
            ushort4 v;
            v.x = tile[s4 * 4 + 0][d]; v.y = tile[s4 * 4 + 1][d];
            v.z = tile[s4 * 4 + 2][d]; v.w = tile[s4 * 4 + 3][d];
            *(ushort4*)(dst + (size_t)(d0 + d) * 4096 + s0 + s4 * 4) = v;
        }
    }
}

// ---------- MFMA flash attention, SPLIT-s=2, round-9.
// grid (16, 16, 4): z = b*2 + chunk; chunk covers s in [chunk*2048, +2048).
// LDS = 40960 B (4 blocks/CU); gload_lds staging w/ pre-swizzled source;
// 2 barriers/iter (Ps wave-private); defer-max (THR=8); no forced VGPR cap.
__global__ __launch_bounds__(256) void attn_mfma_split(const ushort* __restrict__ Qb,
        const ushort* __restrict__ KVb, const ushort* __restrict__ Vt,
        float* __restrict__ Opart, float* __restrict__ ml)
{
    __shared__ ushort Ks[64 * 128];      // 16384 B, swizzled rows of 128 shorts
    __shared__ ushort VsT[128 * 64];     // 16384 B, swizzled rows of 64 shorts
    __shared__ ushort Ps[4 * 16 * 64];   //  8192 B, per-wave 16x64, swizzled

    const int q0 = blockIdx.x * 64;
    const int h = blockIdx.y;
    const int b = blockIdx.z >> 1, chunk = blockIdx.z & 1;
    const int g = h >> 2, p = h & 3;
    const int tid = threadIdx.x;
    const int w = tid >> 6, lane = tid & 63;
    const int quad = lane >> 4, l16 = lane & 15;
    const int sbase = chunk * 2048;

    const ushort* qg = Qb + (size_t)(b * 1024 + q0) * 2048 + h * 128;
    const ushort* kg = KVb + (size_t)g * 8388608ull + (size_t)(b * 4096 + sbase) * 1024 + p * 256;
    const ushort* vg = Vt + (size_t)(b * 16 + h) * 128 * 4096 + sbase;

    // stage Q through Ks (swizzled, manual — runs once), pull per-lane fragments
    {
        int kr = tid >> 4, kc8 = (tid & 15) * 8;
        #pragma unroll
        for (int i = 0; i < 4; ++i) {
            int r = kr + 16 * i;
            *(uint4*)&Ks[r * 128 + SWZ(r, kc8)] = *(const uint4*)(qg + (size_t)r * 2048 + kc8);
        }
    }
    __syncthreads();
    short8 qf[4];
    {
        int qr = w * 16 + l16;
        #pragma unroll
        for (int kc = 0; kc < 4; ++kc)
            qf[kc] = *(const short8*)&Ks[qr * 128 + SWZ(qr, kc * 32 + quad * 8)];
    }

    f32x4 accO[8];
    float m_i[4], l_i[4];
    #pragma unroll
    for (int dt = 0; dt < 8; ++dt) accO[dt] = (f32x4){0.f, 0.f, 0.f, 0.f};
    #pragma unroll
    for (int r = 0; r < 4; ++r) { m_i[r] = -INFINITY; l_i[r] = 0.f; }

    // staging geometry (per-lane, hoisted):
    //   K: wave w rows w*16+i*4+(lane>>4); src col = ((lane&15)*8) ^ ((row&7)<<3)
    //   V: wave w rows w*32+i*8+(lane>>3); src col = ((lane&7)*8) ^ ((row&7)<<3)
    const int k_r4 = lane >> 4;                       // 0..3
    const int k_cb = (lane & 15) * 8;                 // base col (shorts)
    const int v_r8 = lane >> 3;                       // 0..7 ; (row&7)==v_r8&7
    const int v_c  = ((lane & 7) * 8) ^ ((v_r8 & 7) << 3);

    for (int s0 = 0; s0 < 2048; s0 += 64) {
        __syncthreads();                              // all waves done reading tiles
        #pragma unroll
        for (int i = 0; i < 4; ++i) {
            int r = w * 16 + i * 4 + k_r4;            // (r&7) = (i*4 + k_r4)&7
            gload16(kg + (size_t)(s0 + r) * 1024 + (k_cb ^ ((r & 7) << 3)),
                    &Ks[w * 2048 + i * 512]);
        }
        #pragma unroll
        for (int i = 0; i < 4; ++i) {
            int d = w * 32 + i * 8 + v_r8;
            gload16(vg + (size_t)d * 4096 + s0 + v_c,
                    &VsT[w * 2048 + i * 512]);
        }
        __syncthreads();                              // vmcnt(0) drain -> tiles ready
        // QK^T
        f32x4 accS[4];
        #pragma unroll
        for (int st = 0; st < 4; ++st) accS[st] = (f32x4){0.f, 0.f, 0.f, 0.f};
        #pragma unroll
        for (int kc = 0; kc < 4; ++kc) {
            #pragma unroll
            for (int st = 0; st < 4; ++st) {
                int krow = st * 16 + l16;
                short8 kf = *(const short8*)&Ks[krow * 128 + SWZ(krow, kc * 32 + quad * 8)];
                accS[st] = __builtin_amdgcn_mfma_f32_16x16x32_bf16(qf[kc], kf, accS[st], 0, 0, 0);
            }
        }
        // online softmax, defer-max (THR=8): P bounded by e^8, fp32 accum safe
        #pragma unroll
        for (int r = 0; r < 4; ++r) {
            float tm = fmaxf(fmaxf(accS[0][r], accS[1][r]), fmaxf(accS[2][r], accS[3][r]));
            #pragma unroll
            for (int msk = 1; msk < 16; msk <<= 1) tm = fmaxf(tm, __shfl_xor(tm, msk));
            if (tm > m_i[r] + 8.f) {                  // uniform within 16-lane group
                float alpha = __expf(m_i[r] - tm);
                l_i[r] *= alpha;
                #pragma unroll
                for (int dt = 0; dt < 8; ++dt) accO[dt][r] *= alpha;
                m_i[r] = tm;
            }
            const float mn = m_i[r];
            float rs = 0.f;
            const int prow = quad * 4 + r;
            #pragma unroll
            for (int st = 0; st < 4; ++st) {
                float e = __expf(accS[st][r] - mn);
                rs += e;
                Ps[(w * 16 + prow) * 64 + SWZ(prow, st * 16 + l16)] = f2bf(e);
            }
            #pragma unroll
            for (int msk = 1; msk < 16; msk <<= 1) rs += __shfl_xor(rs, msk);
            l_i[r] += rs;
        }
        // Ps is wave-private: no block barrier; intra-wave lgkmcnt orders write->read
        short8 pf[2];
        #pragma unroll
        for (int sc = 0; sc < 2; ++sc)
            pf[sc] = *(const short8*)&Ps[(w * 16 + l16) * 64 + SWZ(l16, sc * 32 + quad * 8)];
        #pragma unroll
        for (int sc = 0; sc < 2; ++sc) {
            #pragma unroll
            for (int dt = 0; dt < 8; ++dt) {
                int vrow = dt * 16 + l16;
                short8 vf = *(const short8*)&VsT[vrow * 64 + SWZ(vrow, sc * 32 + quad * 8)];
                accO[dt] = __builtin_amdgcn_mfma_f32_16x16x32_bf16(pf[sc], vf, accO[dt], 0, 0, 0);
            }
        }
    }
    // epilogue: unnormalized fp32 partials + (m,l)
    const int qrow = q0 + w * 16 + quad * 4;
    float* ob = Opart + (size_t)((chunk * 2 + b) * 1024 + qrow) * 2048 + h * 128 + l16;
    #pragma unroll
    for (int r = 0; r < 4; ++r)
        #pragma unroll
        for (int dt = 0; dt < 8; ++dt)
            ob[(size_t)r * 2048 + dt * 16] = accO[dt][r];
    if (l16 == 0) {
        #pragma unroll
        for (int r = 0; r < 4; ++r) {
            size_t mi = ((size_t)((chunk * 2 + b) * 1024 + qrow + r) * 16 + h) * 2;
            ml[mi] = m_i[r];
            ml[mi + 1] = l_i[r];
        }
    }
}

// ---------- merge the 2 s-chunks: one wave per (b,q,h); lane owns d=lane, lane+64
__global__ __launch_bounds__(256) void attn_merge(const float* __restrict__ Opart,
        const float* __restrict__ ml, ushort* __restrict__ Om)
{
    const int idx = blockIdx.x * 4 + (threadIdx.x >> 6);  // 0..32767
    const int lane = threadIdx.x & 63;
    const int h = idx & 15;
    const int q = (idx >> 4) & 1023;
    const int b = idx >> 14;

    size_t m1i = ((size_t)((0 * 2 + b) * 1024 + q) * 16 + h) * 2;
    size_t m2i = ((size_t)((1 * 2 + b) * 1024 + q) * 16 + h) * 2;
    float m1 = ml[m1i], l1 = ml[m1i + 1];
    float m2 = ml[m2i], l2 = ml[m2i + 1];
    float M = fmaxf(m1, m2);
    float w1 = __expf(m1 - M), w2 = __expf(m2 - M);
    float invL = 1.f / (l1 * w1 + l2 * w2);

    const float* o1 = Opart + (size_t)((0 * 2 + b) * 1024 + q) * 2048 + h * 128;
    const float* o2 = Opart + (size_t)((1 * 2 + b) * 1024 + q) * 2048 + h * 128;
    ushort* ob = Om + (size_t)(b * 1024 + q) * 2048 + h * 128;
    ob[lane]      = f2bf((o1[lane]      * w1 + o2[lane]      * w2) * invL);
    ob[lane + 64] = f2bf((o1[lane + 64] * w1 + o2[lane + 64] * w2) * invL);
}

extern "C" void kernel_launch(void* const* d_in, const int* in_sizes, int n_in,
                              void* d_out, int out_size, void* d_ws, size_t ws_size,
                              hipStream_t stream)
{
    (void)in_sizes; (void)n_in; (void)out_size; (void)ws_size;
    const float* x_q       = (const float*)d_in[0];
    const float* x_kv      = (const float*)d_in[1];
    const float* W_dQ      = (const float*)d_in[2];
    const float* q_norm_w  = (const float*)d_in[3];
    const float* W_uQ      = (const float*)d_in[4];
    const float* W_dKV     = (const float*)d_in[5];
    const float* kv_norm_w = (const float*)d_in[6];
    const float* W_ukv     = (const float*)d_in[7];
    const float* W_o       = (const float*)d_in[8];
    float* out = (float*)d_out;

    float* ws = (float*)d_ws;
    ushort* xkvb       = (ushort*)ws;
    ushort* attn_out_b = (ushort*)ws;
    float*  mlbuf      = ws + 2097152ull;
    ushort* Wot        = (ushort*)(ws + 4194304ull);
    float*  ckv        = ws + 8388608ull;
    float*  Opart      = ws + 8388608ull;                 // aliases dead ckv
    ushort* xqb        = (ushort*)(ws + 8388608ull);      // pre-stage-9 only
    ushort* WdQt       = (ushort*)(ws + 10485760ull);
    float*  q_lat      = ws + 11010048ull;
    ushort* q_lat_b    = (ushort*)(ws + 12058624ull);
    ushort* WuQt       = (ushort*)(ws + 12582912ull);
    ushort* ckv_b      = (ushort*)(ws + 16777216ull);
    ushort* kvgb       = (ushort*)(ws + 20971520ull);
    ushort* vt         = (ushort*)(ws + 37748736ull);
    ushort* qb         = (ushort*)(ws + 46137344ull);
    ushort* WdKVt      = (ushort*)(ws + 48234496ull);
    ushort* Wukvt      = (ushort*)(ws + 49283072ull);

    const float qscale = 0.08838834764831845f;            // 1/sqrt(128)

    // 1-3) q_lat = bf16(x_q) @ bf16(W_dQ)
    cast_bf16<<<2048, 256, 0, stream>>>(x_q, xqb);
    transpose_cast<<<dim3(32, 8, 1), 256, 0, stream>>>(W_dQ, WdQt, 512, 2048, 0, 0, 0);
    gemm_mfma<<<dim3(4, 16), 256, 0, stream>>>(xqb, WdQt, q_lat, 2048, 512, 2048, 2048, 2048, 512, 0, 1.f);
    // 4) rmsnorm -> bf16 (coalesced)
    rms_q_wave<<<512, 256, 0, stream>>>(q_lat, q_norm_w, q_lat_b);
    // 5-6) qb = (q_lat_b @ W_uQ[:, head :128]) * qscale
    transpose_cast<<<dim3(8, 32, 1), 256, 0, stream>>>(W_uQ, WuQt, 3072, 512, 1, 0, 0);
    gemm_mfma<<<dim3(16, 16), 256, 0, stream>>>(q_lat_b, WuQt, qb, 2048, 2048, 512, 512, 512, 2048, 1, qscale);
    // 7-9) ckv = bf16(x_kv) @ bf16(W_dKV[:, :1024])
    cast_bf16<<<8192, 256, 0, stream>>>(x_kv, xkvb);
    transpose_cast<<<dim3(32, 16, 1), 256, 0, stream>>>(W_dKV, WdKVt, 1088, 2048, 0, 0, 0);
    gemm_mfma<<<dim3(8, 64), 256, 0, stream>>>(xkvb, WdKVt, ckv, 8192, 1024, 2048, 2048, 2048, 1024, 0, 1.f);
    // 10) grouped rmsnorm -> bf16 (coalesced)
    rms_kv_wave<<<8192, 256, 0, stream>>>(ckv, kv_norm_w, ckv_b);
    // 11-12) kv up-projection per group -> bf16 kvgb
    transpose_cast<<<dim3(4, 16, 4), 256, 0, stream>>>(W_ukv, Wukvt, 1024, 256, 0, 262144, 262144);
    for (int g = 0; g < 4; ++g)
        gemm_mfma<<<dim3(8, 64), 256, 0, stream>>>(ckv_b + g * 256, Wukvt + (size_t)g * 262144,
                                                   kvgb + (size_t)g * 8388608ull,
                                                   8192, 1024, 256, 1024, 256, 1024, 1, 1.f);
    // 13) V transpose
    transpose_v<<<dim3(64, 2, 32), 256, 0, stream>>>(kvgb, vt);
    // 14) split-s MFMA flash attention + merge
    attn_mfma_split<<<dim3(16, 16, 4), 256, 0, stream>>>(qb, kvgb, vt, Opart, mlbuf);
    attn_merge<<<8192, 256, 0, stream>>>(Opart, mlbuf, attn_out_b);
    // 15-16) out = attn_out_b @ bf16(W_o)
    transpose_cast<<<dim3(32, 32, 1), 256, 0, stream>>>(W_o, Wot, 2048, 2048, 0, 0, 0);
    gemm_mfma<<<dim3(16, 16), 256, 0, stream>>>(attn_out_b, Wot, out, 2048, 2048, 2048, 2048, 2048, 2048, 0, 1.f);
}